// Round 8
// baseline (450.903 us; speedup 1.0000x reference)
//
#include <hip/hip_runtime.h>
#include <hip/hip_fp16.h>
#include <math.h>

#define IN_CH 128
#define HEADS 8
#define HID 16
#define OUT_CH 16
#define NEG 0.2f
#define NPB 256          // nodes per bucket (>>8)
#define MAXBUCK 400

__device__ __forceinline__ float lrelu(float x){ return x > 0.f ? x : NEG * x; }
// bf16 pack/unpack (RNE); weights are positive finite, no NaN path needed
__device__ __forceinline__ unsigned short f2bf(float f){
    unsigned u = __float_as_uint(f);
    return (unsigned short)((u + 0x7FFFu + ((u >> 16) & 1u)) >> 16);
}
__device__ __forceinline__ float bf2f(unsigned short b){ return __uint_as_float((unsigned)b << 16); }

// ---------------- bucketed CSR build ----------------
__global__ __launch_bounds__(256) void k_bhist(const int* __restrict__ tgt, int E, int nbuck, int epb,
                                               int* __restrict__ bcnt){
    __shared__ int hist[MAXBUCK];
    int tid = threadIdx.x;
    for (int i = tid; i < nbuck; i += 256) hist[i] = 0;
    __syncthreads();
    int start = blockIdx.x * epb, end = min(start + epb, E);
    for (int e = start + tid; e < end; e += 256) atomicAdd(&hist[tgt[e] >> 8], 1);
    __syncthreads();
    for (int i = tid; i < nbuck; i += 256) if (hist[i]) atomicAdd(&bcnt[i], hist[i]);
}

__global__ void k_bscan(const int* __restrict__ bcnt, int nbuck, int E,
                        int* __restrict__ boffs, int* __restrict__ bcur){
    __shared__ int s[512];
    int t = threadIdx.x;
    int v = (t < nbuck) ? bcnt[t] : 0;
    int orig = v;
    s[t] = v; __syncthreads();
    for (int off = 1; off < 512; off <<= 1){
        int u = (t >= off) ? s[t - off] : 0;
        __syncthreads();
        v += u; s[t] = v; __syncthreads();
    }
    if (t < nbuck){ boffs[t] = v - orig; bcur[t] = v - orig; }
    if (t == 0) boffs[nbuck] = E;
}

__global__ __launch_bounds__(256) void k_bscatter(const int* __restrict__ ei, int E, int nbuck, int epb,
                                                  int* __restrict__ bcur, int2* __restrict__ ebuck){
    __shared__ int hist[MAXBUCK];
    __shared__ int base[MAXBUCK];
    int tid = threadIdx.x;
    for (int i = tid; i < nbuck; i += 256) hist[i] = 0;
    __syncthreads();
    int start = blockIdx.x * epb, end = min(start + epb, E);
    for (int e = start + tid; e < end; e += 256) atomicAdd(&hist[ei[E + e] >> 8], 1);
    __syncthreads();
    for (int i = tid; i < nbuck; i += 256){
        base[i] = hist[i] ? atomicAdd(&bcur[i], hist[i]) : 0;
        hist[i] = 0;
    }
    __syncthreads();
    for (int e = start + tid; e < end; e += 256){
        int s = ei[e], t = ei[E + e];
        int b = t >> 8;
        int r = atomicAdd(&hist[b], 1);
        ebuck[base[b] + r] = make_int2(s, t);
    }
}

__global__ __launch_bounds__(256) void k_csr(const int2* __restrict__ ebuck, const int* __restrict__ boffs,
                                             int N, int E,
                                             int* __restrict__ offs, int* __restrict__ esrc){
    __shared__ int cnt[256];
    __shared__ int sscan[256];
    __shared__ int wcur[256];
    int b = blockIdx.x;
    int tid = threadIdx.x;
    int n0 = b * 256;
    int nn = min(256, N - n0);
    cnt[tid] = (tid < nn) ? 1 : 0;
    __syncthreads();
    int e0 = boffs[b], e1 = boffs[b + 1];
    for (int e = e0 + tid; e < e1; e += 256) atomicAdd(&cnt[ebuck[e].y & 255], 1);
    __syncthreads();
    int v = cnt[tid], orig = v;
    sscan[tid] = v; __syncthreads();
    for (int off = 1; off < 256; off <<= 1){
        int u = (tid >= off) ? sscan[tid - off] : 0;
        __syncthreads();
        v += u; sscan[tid] = v; __syncthreads();
    }
    int excl = v - orig;
    int gbase = e0 + n0;
    if (tid < nn){
        offs[n0 + tid] = gbase + excl;
        esrc[gbase + excl] = n0 + tid;
    }
    wcur[tid] = excl + 1;
    __syncthreads();
    for (int e = e0 + tid; e < e1; e += 256){
        int2 p = ebuck[e];
        int r = atomicAdd(&wcur[p.y & 255], 1);
        esrc[gbase + r] = p.x;
    }
    if (b == 0 && tid == 0) offs[N] = E + N;
}

// ---------------- GEMM1: h1 = x @ W1 -> fp16 [N][64] half2, k-blocked ----------------
#define FMA4(acc, a, b) { acc.x += (a)*(b).x; acc.y += (a)*(b).y; acc.z += (a)*(b).z; acc.w += (a)*(b).w; }

__global__ __launch_bounds__(256) void k_gemm1(const float* __restrict__ x, const float* __restrict__ W1,
                                               __half2* __restrict__ h1h, int N){
    __shared__ float sW[64*128];
    __shared__ float sA[32*132];
    int tid = threadIdx.x;
    int row0 = blockIdx.x * 32;
    #pragma unroll
    for (int i = 0; i < 4; ++i){
        int q = i*256 + tid;
        int r = q >> 5, kq = q & 31;
        float4 v = make_float4(0.f,0.f,0.f,0.f);
        if (row0 + r < N) v = *(const float4*)(x + (size_t)(row0+r)*128 + kq*4);
        *(float4*)(&sA[r*132 + kq*4]) = v;
    }
    int tr = tid & 7, tc = tid >> 3;
    int c0 = tc*4;
    float4 accv[4] = {make_float4(0,0,0,0), make_float4(0,0,0,0), make_float4(0,0,0,0), make_float4(0,0,0,0)};
    for (int ph = 0; ph < 2; ++ph){
        __syncthreads();
        for (int i = tid; i < 64*128; i += 256) sW[i] = W1[ph*64*128 + i];
        __syncthreads();
        #pragma unroll 4
        for (int k4 = 0; k4 < 16; ++k4){
            int kb = ph*64 + k4*4;
            float4 a0 = *(const float4*)(&sA[(tr+ 0)*132 + kb]);
            float4 a1 = *(const float4*)(&sA[(tr+ 8)*132 + kb]);
            float4 a2 = *(const float4*)(&sA[(tr+16)*132 + kb]);
            float4 a3 = *(const float4*)(&sA[(tr+24)*132 + kb]);
            float4 b0 = *(const float4*)(&sW[(k4*4+0)*128 + c0]);
            float4 b1 = *(const float4*)(&sW[(k4*4+1)*128 + c0]);
            float4 b2 = *(const float4*)(&sW[(k4*4+2)*128 + c0]);
            float4 b3 = *(const float4*)(&sW[(k4*4+3)*128 + c0]);
            FMA4(accv[0], a0.x, b0); FMA4(accv[0], a0.y, b1); FMA4(accv[0], a0.z, b2); FMA4(accv[0], a0.w, b3);
            FMA4(accv[1], a1.x, b0); FMA4(accv[1], a1.y, b1); FMA4(accv[1], a1.z, b2); FMA4(accv[1], a1.w, b3);
            FMA4(accv[2], a2.x, b0); FMA4(accv[2], a2.y, b1); FMA4(accv[2], a2.z, b2); FMA4(accv[2], a2.w, b3);
            FMA4(accv[3], a3.x, b0); FMA4(accv[3], a3.y, b1); FMA4(accv[3], a3.z, b2); FMA4(accv[3], a3.w, b3);
        }
    }
    #pragma unroll
    for (int i = 0; i < 4; ++i){
        int r = row0 + tr + 8*i;
        if (r < N){
            __half2 p0 = __floats2half2_rn(accv[i].x, accv[i].y);
            __half2 p1 = __floats2half2_rn(accv[i].z, accv[i].w);
            __half2* dst = h1h + (size_t)r*64 + (c0 >> 1);
            dst[0] = p0; dst[1] = p1;
        }
    }
}

// ---------------- attention logits, layer 1 ----------------
struct H8 { __half2 v[8]; };

__global__ void k_alpha1(const __half2* __restrict__ h1h, const float* __restrict__ asrc, const float* __restrict__ adst,
                         float* __restrict__ as1, float* __restrict__ ad1, int N){
    int idx = blockIdx.x*blockDim.x + threadIdx.x;
    if (idx >= N*HEADS) return;
    int h = idx & 7;
    int n = idx >> 3;
    H8 blk = *(const H8*)(h1h + (size_t)n*64 + h*8);
    const float2* sp = (const float2*)(asrc + h*16);
    const float2* dp = (const float2*)(adst + h*16);
    float ss = 0.f, dd = 0.f;
    #pragma unroll
    for (int j = 0; j < 8; ++j){
        float2 v = __half22float2(blk.v[j]);
        float2 a = sp[j], b = dp[j];
        ss += v.x*a.x + v.y*a.y;
        dd += v.x*b.x + v.y*b.y;
    }
    as1[idx] = ss; ad1[idx] = dd;
}

// ---------------- per-edge weights, layer 1 (bf16) ----------------
// one wave per node; lane l = (slot l>>3, head l&7). Writes are lane-contiguous:
// addr = (e0+g)*8 + l for each 8-edge group -> coalesced 128B.
__global__ __launch_bounds__(256) void k_w1(const float* __restrict__ as1, const float* __restrict__ ad1,
                                            const int* __restrict__ offs, const int* __restrict__ esrc,
                                            unsigned short* __restrict__ w1, int N){
    int n = blockIdx.x*4 + (threadIdx.x >> 6);
    if (n >= N) return;
    int l = threadIdx.x & 63;
    int slot = l >> 3, hw = l & 7;
    float ad = ad1[n*8 + hw];
    int e0 = offs[n], e1 = offs[n+1];
    for (int e = e0 + slot; e < e1; e += 8){
        int s = esrc[e];
        float w = __expf(lrelu(as1[s*8 + hw] + ad));
        w1[(size_t)e*8 + hw] = f2bf(w);
    }
}

// ---------------- layer-1 aggregation: precomputed weights, single pass ----------------
// round-6 structure; weight gather+exp replaced by sequential bf16 load.
__global__ __launch_bounds__(256) void k_agg1(const __half2* __restrict__ h1h, const unsigned short* __restrict__ w1,
                                              const int* __restrict__ offs, const int* __restrict__ esrc,
                                              const float* __restrict__ b1, __half2* __restrict__ hl2h, int N){
    int n = blockIdx.x*4 + (threadIdx.x >> 6);
    if (n >= N) return;
    int l = threadIdx.x & 63;
    int h = l >> 3;
    int e0 = offs[n], e1 = offs[n+1];

    float2 acc0 = make_float2(0.f,0.f), acc1 = make_float2(0.f,0.f);
    float den0 = 0.f, den1 = 0.f;
    int e = e0;
    for (; e + 2 <= e1; e += 2){
        int s0 = esrc[e], s1 = esrc[e+1];
        float w0 = bf2f(w1[(size_t)e*8 + h]);
        float w1v = bf2f(w1[(size_t)(e+1)*8 + h]);
        float2 h0 = __half22float2(h1h[(size_t)s0*64 + l]);
        float2 h1v = __half22float2(h1h[(size_t)s1*64 + l]);
        den0 += w0; den1 += w1v;
        acc0.x += w0*h0.x;   acc0.y += w0*h0.y;
        acc1.x += w1v*h1v.x; acc1.y += w1v*h1v.y;
    }
    if (e < e1){
        int s0 = esrc[e];
        float w0 = bf2f(w1[(size_t)e*8 + h]);
        float2 h0 = __half22float2(h1h[(size_t)s0*64 + l]);
        den0 += w0;
        acc0.x += w0*h0.x; acc0.y += w0*h0.y;
    }
    float rd = 1.f / (den0 + den1 + 1e-16f);
    float2 bb = ((const float2*)b1)[l];
    float vx = (acc0.x + acc1.x)*rd + bb.x;
    float vy = (acc0.y + acc1.y)*rd + bb.y;
    vx = vx > 0.f ? vx : expm1f(vx);
    vy = vy > 0.f ? vy : expm1f(vy);
    hl2h[(size_t)n*64 + l] = __floats2half2_rn(vx, vy);
}

// ---------------- GEMM2: h2 = hl2 @ W2 + fused alpha2 ----------------
__global__ __launch_bounds__(256) void k_gemm2(const __half2* __restrict__ hl2h, const float* __restrict__ W2,
                                               const float* __restrict__ asrc2, const float* __restrict__ adst2,
                                               float* __restrict__ h2, float* __restrict__ as2, float* __restrict__ ad2,
                                               int N){
    __shared__ float sX[64*132];
    __shared__ float sW2[128*16];
    int tid = threadIdx.x;
    for (int i = tid; i < 128*16; i += 256) sW2[i] = W2[i];
    int row0 = blockIdx.x * 64;
    #pragma unroll
    for (int i = 0; i < 4; ++i){
        int q = i*256 + tid;
        int r = q >> 4, seg = q & 15;
        float4 raw = make_float4(0.f,0.f,0.f,0.f);
        if (row0 + r < N) raw = ((const float4*)(hl2h + (size_t)(row0+r)*64))[seg];
        const __half2* hp = (const __half2*)&raw;
        float* dst = &sX[r*132 + seg*8];
        #pragma unroll
        for (int j = 0; j < 4; ++j){
            float2 f = __half22float2(hp[j]);
            dst[2*j] = f.x; dst[2*j+1] = f.y;
        }
    }
    __syncthreads();
    int nd = tid >> 2;
    int cq = tid & 3, c0 = cq*4;
    int n = row0 + nd;
    float4 acc = make_float4(0.f,0.f,0.f,0.f);
    #pragma unroll 4
    for (int k4 = 0; k4 < 32; ++k4){
        float4 a  = *(const float4*)(&sX[nd*132 + k4*4]);
        float4 w0 = *(const float4*)(&sW2[(k4*4+0)*16 + c0]);
        float4 w1 = *(const float4*)(&sW2[(k4*4+1)*16 + c0]);
        float4 w2 = *(const float4*)(&sW2[(k4*4+2)*16 + c0]);
        float4 w3 = *(const float4*)(&sW2[(k4*4+3)*16 + c0]);
        FMA4(acc, a.x, w0); FMA4(acc, a.y, w1); FMA4(acc, a.z, w2); FMA4(acc, a.w, w3);
    }
    float ps = acc.x*asrc2[c0] + acc.y*asrc2[c0+1] + acc.z*asrc2[c0+2] + acc.w*asrc2[c0+3];
    float pd = acc.x*adst2[c0] + acc.y*adst2[c0+1] + acc.z*adst2[c0+2] + acc.w*adst2[c0+3];
    ps += __shfl_xor(ps, 1); ps += __shfl_xor(ps, 2);
    pd += __shfl_xor(pd, 1); pd += __shfl_xor(pd, 2);
    if (n < N){
        *(float4*)(&h2[(size_t)n*16 + c0]) = acc;
        if (cq == 0){ as2[n] = ps; ad2[n] = pd; }
    }
}

// ---------------- per-edge weights, layer 2 (fp32) ----------------
__global__ __launch_bounds__(256) void k_w2(const float* __restrict__ as2v, const float* __restrict__ ad2v,
                                            const int* __restrict__ offs, const int* __restrict__ esrc,
                                            float* __restrict__ w2, int N){
    int n = blockIdx.x*4 + (threadIdx.x >> 6);
    if (n >= N) return;
    int l = threadIdx.x & 63;
    float ad = ad2v[n];
    int e0 = offs[n], e1 = offs[n+1];
    for (int e = e0 + l; e < e1; e += 64)
        w2[e] = __expf(lrelu(as2v[esrc[e]] + ad));
}

// ---------------- layer-2 aggregation: precomputed weights -> out ----------------
__global__ __launch_bounds__(256) void k_agg2(const float* __restrict__ h2, const float* __restrict__ w2,
                                              const int* __restrict__ offs, const int* __restrict__ esrc,
                                              const float* __restrict__ b2, float* __restrict__ out, int N){
    int n = blockIdx.x*4 + (threadIdx.x >> 6);
    if (n >= N) return;
    int l = threadIdx.x & 63;
    int e0 = offs[n], e1 = offs[n+1];
    int eo = l >> 4, c = l & 15;
    float acc0 = 0.f, acc1 = 0.f, den0 = 0.f, den1 = 0.f;
    int e = e0 + eo;
    for (; e + 4 < e1; e += 8){
        int s0 = esrc[e], s1 = esrc[e+4];
        float w0 = w2[e], w1v = w2[e+4];
        den0 += w0; den1 += w1v;
        acc0 += w0 * h2[(size_t)s0*16 + c];
        acc1 += w1v * h2[(size_t)s1*16 + c];
    }
    if (e < e1){
        int s0 = esrc[e];
        float w0 = w2[e];
        den0 += w0;
        acc0 += w0 * h2[(size_t)s0*16 + c];
    }
    float acc = acc0 + acc1, den = den0 + den1;
    acc += __shfl_xor(acc, 16); den += __shfl_xor(den, 16);
    acc += __shfl_xor(acc, 32); den += __shfl_xor(den, 32);
    if (eo == 0) out[(size_t)n*16 + c] = acc / (den + 1e-16f) + b2[c];
}

extern "C" void kernel_launch(void* const* d_in, const int* in_sizes, int n_in,
                              void* d_out, int out_size, void* d_ws, size_t ws_size,
                              hipStream_t stream){
    const float* x     = (const float*)d_in[0];
    const int*   ei    = (const int*)  d_in[1];
    const float* W1    = (const float*)d_in[2];
    const float* asrc1 = (const float*)d_in[3];
    const float* adst1 = (const float*)d_in[4];
    const float* b1    = (const float*)d_in[5];
    const float* W2    = (const float*)d_in[6];
    const float* asrc2 = (const float*)d_in[7];
    const float* adst2 = (const float*)d_in[8];
    const float* b2    = (const float*)d_in[9];
    float* out = (float*)d_out;

    const int N = in_sizes[0] / IN_CH;   // 100000
    const int E = in_sizes[1] / 2;       // 1600000
    const int ETOT = E + N;
    const int NBUCK = (N + NPB - 1) / NPB;   // 391

    char* p = (char*)d_ws;
    auto alloc = [&](size_t bytes) -> char* {
        char* r = p; p += (bytes + 255) & ~(size_t)255; return r;
    };
    __half2* h1h  = (__half2*)alloc((size_t)N * 64 * 4);
    __half2* hl2h = (__half2*)alloc((size_t)N * 64 * 4);
    float* as1   = (float*)alloc((size_t)N * 8 * 4);
    float* ad1   = (float*)alloc((size_t)N * 8 * 4);
    float* h2    = (float*)alloc((size_t)N * 16 * 4);
    float* as2   = (float*)alloc((size_t)N * 4);
    float* ad2   = (float*)alloc((size_t)N * 4);
    int*   bcnt  = (int*)  alloc((size_t)MAXBUCK * 4);
    int*   boffs = (int*)  alloc((size_t)(MAXBUCK + 1) * 4);
    int*   bcur  = (int*)  alloc((size_t)MAXBUCK * 4);
    int*   offs  = (int*)  alloc((size_t)(N + 1) * 4);
    int*   esrc  = (int*)  alloc((size_t)ETOT * 4);
    unsigned short* w1 = (unsigned short*)alloc((size_t)ETOT * 8 * 2);  // 27.2 MB bf16
    int2*  ebuck = (int2*)hl2h;   // aliases hl2h; k_csr done before k_agg1 writes it
    float* w2    = (float*)h1h;   // aliases h1h;  h1h dead after k_agg1, k_w2 runs after

    hipMemsetAsync(bcnt, 0, (size_t)NBUCK * 4, stream);

    const int GPART = 512;
    const int epb = (E + GPART - 1) / GPART;

    k_bhist   <<<GPART, 256, 0, stream>>>(ei + E, E, NBUCK, epb, bcnt);
    k_bscan   <<<1,     512, 0, stream>>>(bcnt, NBUCK, E, boffs, bcur);
    k_bscatter<<<GPART, 256, 0, stream>>>(ei, E, NBUCK, epb, bcur, ebuck);
    k_csr     <<<NBUCK, 256, 0, stream>>>(ebuck, boffs, N, E, offs, esrc);

    k_gemm1  <<<(N + 31) / 32, 256, 0, stream>>>(x, W1, h1h, N);
    k_alpha1 <<<(N * HEADS + 255) / 256, 256, 0, stream>>>(h1h, asrc1, adst1, as1, ad1, N);
    k_w1     <<<(N + 3) / 4, 256, 0, stream>>>(as1, ad1, offs, esrc, w1, N);
    k_agg1   <<<(N + 3) / 4, 256, 0, stream>>>(h1h, w1, offs, esrc, b1, hl2h, N);
    k_gemm2  <<<(N + 63) / 64, 256, 0, stream>>>(hl2h, W2, asrc2, adst2, h2, as2, ad2, N);
    k_w2     <<<(N + 3) / 4, 256, 0, stream>>>(as2, ad2, offs, esrc, w2, N);
    k_agg2   <<<(N + 3) / 4, 256, 0, stream>>>(h2, w2, offs, esrc, b2, out, N);
}

// Round 9
// 356.496 us; speedup vs baseline: 1.2648x; 1.2648x over previous
//
#include <hip/hip_runtime.h>
#include <hip/hip_fp16.h>
#include <math.h>

#define IN_CH 128
#define HEADS 8
#define HID 16
#define OUT_CH 16
#define NEG 0.2f
#define NPB 256          // nodes per bucket (>>8)
#define MAXBUCK 400
#define AST 136          // LDS k-stride in halfs (128 + 8 pad)

__device__ __forceinline__ float lrelu(float x){ return x > 0.f ? x : NEG * x; }

typedef _Float16 half8 __attribute__((ext_vector_type(8)));
typedef float    f32x4 __attribute__((ext_vector_type(4)));

// ---------------- bucketed CSR build ----------------
__global__ __launch_bounds__(256) void k_bhist(const int* __restrict__ tgt, int E, int nbuck, int epb,
                                               int* __restrict__ bcnt){
    __shared__ int hist[MAXBUCK];
    int tid = threadIdx.x;
    for (int i = tid; i < nbuck; i += 256) hist[i] = 0;
    __syncthreads();
    int start = blockIdx.x * epb, end = min(start + epb, E);
    for (int e = start + tid; e < end; e += 256) atomicAdd(&hist[tgt[e] >> 8], 1);
    __syncthreads();
    for (int i = tid; i < nbuck; i += 256) if (hist[i]) atomicAdd(&bcnt[i], hist[i]);
}

__global__ void k_bscan(const int* __restrict__ bcnt, int nbuck, int E,
                        int* __restrict__ boffs, int* __restrict__ bcur){
    __shared__ int s[512];
    int t = threadIdx.x;
    int v = (t < nbuck) ? bcnt[t] : 0;
    int orig = v;
    s[t] = v; __syncthreads();
    for (int off = 1; off < 512; off <<= 1){
        int u = (t >= off) ? s[t - off] : 0;
        __syncthreads();
        v += u; s[t] = v; __syncthreads();
    }
    if (t < nbuck){ boffs[t] = v - orig; bcur[t] = v - orig; }
    if (t == 0) boffs[nbuck] = E;
}

__global__ __launch_bounds__(256) void k_bscatter(const int* __restrict__ ei, int E, int nbuck, int epb,
                                                  int* __restrict__ bcur, int2* __restrict__ ebuck){
    __shared__ int hist[MAXBUCK];
    __shared__ int base[MAXBUCK];
    int tid = threadIdx.x;
    for (int i = tid; i < nbuck; i += 256) hist[i] = 0;
    __syncthreads();
    int start = blockIdx.x * epb, end = min(start + epb, E);
    for (int e = start + tid; e < end; e += 256) atomicAdd(&hist[ei[E + e] >> 8], 1);
    __syncthreads();
    for (int i = tid; i < nbuck; i += 256){
        base[i] = hist[i] ? atomicAdd(&bcur[i], hist[i]) : 0;
        hist[i] = 0;
    }
    __syncthreads();
    for (int e = start + tid; e < end; e += 256){
        int s = ei[e], t = ei[E + e];
        int b = t >> 8;
        int r = atomicAdd(&hist[b], 1);
        ebuck[base[b] + r] = make_int2(s, t);
    }
}

__global__ __launch_bounds__(256) void k_csr(const int2* __restrict__ ebuck, const int* __restrict__ boffs,
                                             int N, int E,
                                             int* __restrict__ offs, int* __restrict__ esrc){
    __shared__ int cnt[256];
    __shared__ int sscan[256];
    __shared__ int wcur[256];
    int b = blockIdx.x;
    int tid = threadIdx.x;
    int n0 = b * 256;
    int nn = min(256, N - n0);
    cnt[tid] = (tid < nn) ? 1 : 0;
    __syncthreads();
    int e0 = boffs[b], e1 = boffs[b + 1];
    for (int e = e0 + tid; e < e1; e += 256) atomicAdd(&cnt[ebuck[e].y & 255], 1);
    __syncthreads();
    int v = cnt[tid], orig = v;
    sscan[tid] = v; __syncthreads();
    for (int off = 1; off < 256; off <<= 1){
        int u = (tid >= off) ? sscan[tid - off] : 0;
        __syncthreads();
        v += u; sscan[tid] = v; __syncthreads();
    }
    int excl = v - orig;
    int gbase = e0 + n0;
    if (tid < nn){
        offs[n0 + tid] = gbase + excl;
        esrc[gbase + excl] = n0 + tid;
    }
    wcur[tid] = excl + 1;
    __syncthreads();
    for (int e = e0 + tid; e < e1; e += 256){
        int2 p = ebuck[e];
        int r = atomicAdd(&wcur[p.y & 255], 1);
        esrc[gbase + r] = p.x;
    }
    if (b == 0 && tid == 0) offs[N] = E + N;
}

// ---------------- GEMM1 (MFMA fp16): h1 = x @ W1 -> fp16 [N][128] ----------------
// block 256 = 4 waves; tile 64 rows x 128 cols; wave w owns rows 16w..16w+15.
// LDS: sA[row][k] halfs (AST-padded), sB[col][k] halfs (W1 transposed).
// mfma_f32_16x16x32_f16: A[m=lane&15][k=(lane>>4)*8+j], B[n=lane&15][k=(lane>>4)*8+j],
// D col=lane&15, row=(lane>>4)*4+reg.
__global__ __launch_bounds__(256) void k_gemm1(const float* __restrict__ x, const float* __restrict__ W1,
                                               __half* __restrict__ h1, int N){
    __shared__ _Float16 sA[64*AST];    // 17.4 KB
    __shared__ _Float16 sB[128*AST];   // 34.8 KB
    int tid = threadIdx.x;
    // stage W1 (fp32 [k][c]) -> sB[c*AST+k] fp16   (global coalesced read)
    for (int i = tid; i < 128*128; i += 256){
        int k = i >> 7, c = i & 127;
        sB[c*AST + k] = (_Float16)W1[i];
    }
    // stage x tile: 64 rows x 128 fp32 -> sA fp16
    int row0 = blockIdx.x * 64;
    #pragma unroll
    for (int i = 0; i < 8; ++i){
        int q = i*256 + tid;            // 2048 float4 slots: 64 rows x 32 segs
        int r = q >> 5, seg = q & 31;
        float4 v = make_float4(0.f,0.f,0.f,0.f);
        if (row0 + r < N) v = *(const float4*)(x + (size_t)(row0+r)*128 + seg*4);
        _Float16* dst = &sA[r*AST + seg*4];
        dst[0]=(_Float16)v.x; dst[1]=(_Float16)v.y; dst[2]=(_Float16)v.z; dst[3]=(_Float16)v.w;
    }
    __syncthreads();
    int wave = tid >> 6, lane = tid & 63;
    int m = lane & 15, quad = lane >> 4;
    int rbase = wave * 16;
    f32x4 acc[8] = {};
    #pragma unroll
    for (int kc = 0; kc < 4; ++kc){
        int kb = kc*32 + quad*8;
        half8 a = *(half8*)(&sA[(rbase + m)*AST + kb]);
        #pragma unroll
        for (int t = 0; t < 8; ++t){
            half8 b = *(half8*)(&sB[(t*16 + m)*AST + kb]);
            acc[t] = __builtin_amdgcn_mfma_f32_16x16x32_f16(a, b, acc[t], 0, 0, 0);
        }
    }
    #pragma unroll
    for (int t = 0; t < 8; ++t){
        #pragma unroll
        for (int j = 0; j < 4; ++j){
            int r = row0 + rbase + quad*4 + j;
            if (r < N) h1[(size_t)r*128 + t*16 + m] = __float2half(acc[t][j]);
        }
    }
}

// ---------------- attention logits, layer 1 ----------------
struct H8 { __half2 v[8]; };

__global__ void k_alpha1(const __half2* __restrict__ h1h, const float* __restrict__ asrc, const float* __restrict__ adst,
                         float* __restrict__ as1, float* __restrict__ ad1, int N){
    int idx = blockIdx.x*blockDim.x + threadIdx.x;
    if (idx >= N*HEADS) return;
    int h = idx & 7;
    int n = idx >> 3;
    H8 blk = *(const H8*)(h1h + (size_t)n*64 + h*8);
    const float2* sp = (const float2*)(asrc + h*16);
    const float2* dp = (const float2*)(adst + h*16);
    float ss = 0.f, dd = 0.f;
    #pragma unroll
    for (int j = 0; j < 8; ++j){
        float2 v = __half22float2(blk.v[j]);
        float2 a = sp[j], b = dp[j];
        ss += v.x*a.x + v.y*a.y;
        dd += v.x*b.x + v.y*b.y;
    }
    as1[idx] = ss; ad1[idx] = dd;
}

// ---------------- layer-1 fused aggregation: single pass, shift-free, 4-wide ----------------
__global__ __launch_bounds__(256) void k_agg1(const __half2* __restrict__ h1h, const float* __restrict__ as1,
                                              const float* __restrict__ ad1,
                                              const int* __restrict__ offs, const int* __restrict__ esrc,
                                              const float* __restrict__ b1, __half2* __restrict__ hl2h, int N){
    int n = blockIdx.x*4 + (threadIdx.x >> 6);
    if (n >= N) return;
    int l = threadIdx.x & 63;
    int h = l >> 3;
    float adh = ad1[n*8 + h];
    int e0 = offs[n], e1 = offs[n+1];

    float2 acc0 = make_float2(0.f,0.f), acc1 = make_float2(0.f,0.f);
    float2 acc2 = make_float2(0.f,0.f), acc3 = make_float2(0.f,0.f);
    float den0 = 0.f, den1 = 0.f, den2 = 0.f, den3 = 0.f;
    int e = e0;
    for (; e + 4 <= e1; e += 4){
        int s0 = esrc[e], s1 = esrc[e+1], s2 = esrc[e+2], s3 = esrc[e+3];
        float a0 = as1[s0*8 + h], a1 = as1[s1*8 + h];
        float a2 = as1[s2*8 + h], a3 = as1[s3*8 + h];
        float2 h0 = __half22float2(h1h[(size_t)s0*64 + l]);
        float2 h1v = __half22float2(h1h[(size_t)s1*64 + l]);
        float2 h2v = __half22float2(h1h[(size_t)s2*64 + l]);
        float2 h3v = __half22float2(h1h[(size_t)s3*64 + l]);
        float w0 = __expf(lrelu(a0 + adh));
        float w1 = __expf(lrelu(a1 + adh));
        float w2 = __expf(lrelu(a2 + adh));
        float w3 = __expf(lrelu(a3 + adh));
        den0 += w0; den1 += w1; den2 += w2; den3 += w3;
        acc0.x += w0*h0.x;  acc0.y += w0*h0.y;
        acc1.x += w1*h1v.x; acc1.y += w1*h1v.y;
        acc2.x += w2*h2v.x; acc2.y += w2*h2v.y;
        acc3.x += w3*h3v.x; acc3.y += w3*h3v.y;
    }
    for (; e < e1; ++e){
        int s0 = esrc[e];
        float w0 = __expf(lrelu(as1[s0*8 + h] + adh));
        float2 h0 = __half22float2(h1h[(size_t)s0*64 + l]);
        den0 += w0;
        acc0.x += w0*h0.x; acc0.y += w0*h0.y;
    }
    float rd = 1.f / (den0 + den1 + den2 + den3 + 1e-16f);
    float2 bb = ((const float2*)b1)[l];
    float vx = (acc0.x + acc1.x + acc2.x + acc3.x)*rd + bb.x;
    float vy = (acc0.y + acc1.y + acc2.y + acc3.y)*rd + bb.y;
    vx = vx > 0.f ? vx : expm1f(vx);
    vy = vy > 0.f ? vy : expm1f(vy);
    hl2h[(size_t)n*64 + l] = __floats2half2_rn(vx, vy);
}

// ---------------- GEMM2: h2 = hl2 @ W2 + fused alpha2 ----------------
#define FMA4(acc, a, b) { acc.x += (a)*(b).x; acc.y += (a)*(b).y; acc.z += (a)*(b).z; acc.w += (a)*(b).w; }

__global__ __launch_bounds__(256) void k_gemm2(const __half2* __restrict__ hl2h, const float* __restrict__ W2,
                                               const float* __restrict__ asrc2, const float* __restrict__ adst2,
                                               float* __restrict__ h2, float* __restrict__ as2, float* __restrict__ ad2,
                                               int N){
    __shared__ float sX[64*132];
    __shared__ float sW2[128*16];
    int tid = threadIdx.x;
    for (int i = tid; i < 128*16; i += 256) sW2[i] = W2[i];
    int row0 = blockIdx.x * 64;
    #pragma unroll
    for (int i = 0; i < 4; ++i){
        int q = i*256 + tid;
        int r = q >> 4, seg = q & 15;
        float4 raw = make_float4(0.f,0.f,0.f,0.f);
        if (row0 + r < N) raw = ((const float4*)(hl2h + (size_t)(row0+r)*64))[seg];
        const __half2* hp = (const __half2*)&raw;
        float* dst = &sX[r*132 + seg*8];
        #pragma unroll
        for (int j = 0; j < 4; ++j){
            float2 f = __half22float2(hp[j]);
            dst[2*j] = f.x; dst[2*j+1] = f.y;
        }
    }
    __syncthreads();
    int nd = tid >> 2;
    int cq = tid & 3, c0 = cq*4;
    int n = row0 + nd;
    float4 acc = make_float4(0.f,0.f,0.f,0.f);
    #pragma unroll 4
    for (int k4 = 0; k4 < 32; ++k4){
        float4 a  = *(const float4*)(&sX[nd*132 + k4*4]);
        float4 w0 = *(const float4*)(&sW2[(k4*4+0)*16 + c0]);
        float4 w1 = *(const float4*)(&sW2[(k4*4+1)*16 + c0]);
        float4 w2 = *(const float4*)(&sW2[(k4*4+2)*16 + c0]);
        float4 w3 = *(const float4*)(&sW2[(k4*4+3)*16 + c0]);
        FMA4(acc, a.x, w0); FMA4(acc, a.y, w1); FMA4(acc, a.z, w2); FMA4(acc, a.w, w3);
    }
    float ps = acc.x*asrc2[c0] + acc.y*asrc2[c0+1] + acc.z*asrc2[c0+2] + acc.w*asrc2[c0+3];
    float pd = acc.x*adst2[c0] + acc.y*adst2[c0+1] + acc.z*adst2[c0+2] + acc.w*adst2[c0+3];
    ps += __shfl_xor(ps, 1); ps += __shfl_xor(ps, 2);
    pd += __shfl_xor(pd, 1); pd += __shfl_xor(pd, 2);
    if (n < N){
        *(float4*)(&h2[(size_t)n*16 + c0]) = acc;
        if (cq == 0){ as2[n] = ps; ad2[n] = pd; }
    }
}

// ---------------- layer-2 fused aggregation: single pass, shift-free -> out ----------------
__global__ __launch_bounds__(256) void k_agg2(const float* __restrict__ h2, const float* __restrict__ as2v,
                                              const float* __restrict__ ad2v,
                                              const int* __restrict__ offs, const int* __restrict__ esrc,
                                              const float* __restrict__ b2, float* __restrict__ out, int N){
    int n = blockIdx.x*4 + (threadIdx.x >> 6);
    if (n >= N) return;
    int l = threadIdx.x & 63;
    int e0 = offs[n], e1 = offs[n+1];
    float ad = ad2v[n];
    int eo = l >> 4, c = l & 15;
    float acc = 0.f, den = 0.f;
    for (int e = e0 + eo; e < e1; e += 4){
        int s = esrc[e];
        float w = __expf(lrelu(as2v[s] + ad));
        den += w;
        acc += w * h2[(size_t)s*16 + c];
    }
    acc += __shfl_xor(acc, 16); den += __shfl_xor(den, 16);
    acc += __shfl_xor(acc, 32); den += __shfl_xor(den, 32);
    if (eo == 0) out[(size_t)n*16 + c] = acc / (den + 1e-16f) + b2[c];
}

extern "C" void kernel_launch(void* const* d_in, const int* in_sizes, int n_in,
                              void* d_out, int out_size, void* d_ws, size_t ws_size,
                              hipStream_t stream){
    const float* x     = (const float*)d_in[0];
    const int*   ei    = (const int*)  d_in[1];
    const float* W1    = (const float*)d_in[2];
    const float* asrc1 = (const float*)d_in[3];
    const float* adst1 = (const float*)d_in[4];
    const float* b1    = (const float*)d_in[5];
    const float* W2    = (const float*)d_in[6];
    const float* asrc2 = (const float*)d_in[7];
    const float* adst2 = (const float*)d_in[8];
    const float* b2    = (const float*)d_in[9];
    float* out = (float*)d_out;

    const int N = in_sizes[0] / IN_CH;   // 100000
    const int E = in_sizes[1] / 2;       // 1600000
    const int ETOT = E + N;
    const int NBUCK = (N + NPB - 1) / NPB;   // 391

    char* p = (char*)d_ws;
    auto alloc = [&](size_t bytes) -> char* {
        char* r = p; p += (bytes + 255) & ~(size_t)255; return r;
    };
    __half2* h1h  = (__half2*)alloc((size_t)N * 64 * 4);
    __half2* hl2h = (__half2*)alloc((size_t)N * 64 * 4);
    float* as1   = (float*)alloc((size_t)N * 8 * 4);
    float* ad1   = (float*)alloc((size_t)N * 8 * 4);
    float* h2    = (float*)alloc((size_t)N * 16 * 4);
    float* as2   = (float*)alloc((size_t)N * 4);
    float* ad2   = (float*)alloc((size_t)N * 4);
    int*   bcnt  = (int*)  alloc((size_t)MAXBUCK * 4);
    int*   boffs = (int*)  alloc((size_t)(MAXBUCK + 1) * 4);
    int*   bcur  = (int*)  alloc((size_t)MAXBUCK * 4);
    int*   offs  = (int*)  alloc((size_t)(N + 1) * 4);
    int*   esrc  = (int*)  alloc((size_t)ETOT * 4);
    int2*  ebuck = (int2*)hl2h;   // aliases hl2h; k_csr done before k_agg1 writes it

    hipMemsetAsync(bcnt, 0, (size_t)NBUCK * 4, stream);

    const int GPART = 512;
    const int epb = (E + GPART - 1) / GPART;

    k_bhist   <<<GPART, 256, 0, stream>>>(ei + E, E, NBUCK, epb, bcnt);
    k_bscan   <<<1,     512, 0, stream>>>(bcnt, NBUCK, E, boffs, bcur);
    k_bscatter<<<GPART, 256, 0, stream>>>(ei, E, NBUCK, epb, bcur, ebuck);
    k_csr     <<<NBUCK, 256, 0, stream>>>(ebuck, boffs, N, E, offs, esrc);

    k_gemm1  <<<(N + 63) / 64, 256, 0, stream>>>(x, W1, (__half*)h1h, N);
    k_alpha1 <<<(N * HEADS + 255) / 256, 256, 0, stream>>>(h1h, asrc1, adst1, as1, ad1, N);
    k_agg1   <<<(N + 3) / 4, 256, 0, stream>>>(h1h, as1, ad1, offs, esrc, b1, hl2h, N);
    k_gemm2  <<<(N + 63) / 64, 256, 0, stream>>>(hl2h, W2, asrc2, adst2, h2, as2, ad2, N);
    k_agg2   <<<(N + 3) / 4, 256, 0, stream>>>(h2, as2, ad2, offs, esrc, b2, out, N);
}